// Round 1
// 1975.721 us; speedup vs baseline: 1.5376x; 1.5376x over previous
//
#include <hip/hip_runtime.h>
#include <cstdint>

#define TT 2048
#define NH 15

typedef _Float16 half8 __attribute__((ext_vector_type(8)));
typedef float f32x4 __attribute__((ext_vector_type(4)));
typedef int int4v __attribute__((ext_vector_type(4)));

#define EXP2(x) __builtin_amdgcn_exp2f(x)
#define RCP(x) __builtin_amdgcn_rcpf(x)
#define SIGM(x) (RCP(1.0f + EXP2((x) * -1.4426950408889634f)))
#define TANHF(x) (fmaf(-2.0f, RCP(1.0f + EXP2((x) * 2.8853900817779268f)), 1.0f))
#define BPERM(addr, v) __builtin_amdgcn_ds_bpermute((addr), (v))
#define PKRTZ_I(a, b) __builtin_bit_cast(int, __builtin_amdgcn_cvt_pkrtz((a), (b)))

// MFMA formulation, layer-wavefront staggered.
// One wave = 16 batch elements, all 3 cells, all T steps.
// Per cell: Z[64x16] = Wp[64x32] x V[32x16], 4x mfma_f32_16x16x32_f16.
//
// Fragment maps (m89-verified): A[m=lane&15][k=(lane>>4)*8+j];
// B[k][n=lane&15], same k map; D col=lane&15, row=(lane>>4)*4+r.
// So lane (q,n) owns D rows (units) 4q..4q+3 of element n, and holds
// B rows k=8q..8q+7 of column n.
//
// Interleaved-K layout (NEW): k = 8q+j with
//   j<4  -> "in"  unit u = 4q+j   (prev-cell h; cell1: h1_prev, u15 = x)
//   j>=4 -> "own" unit u = 4q+j-4 (own recurrent h; u15 = bias 1.0)
// With this layout the B fragment is LANE-LOCAL: dwords =
//   { pk(in0,in1), pk(in2,in3), pk(own0,own1), pk(own2,own3) }
// -> zero ds_bpermute per cell (was 8-12/step). Unit-15 pad state is
// provably 0 (zero A row -> z=0 -> c,h stay 0), so q==3 high halves are
// correct; x and bias are injected at the u15 slots (k=27 / k=31).
//
// Stagger: at START of iteration i: h1f=h1(i-1), h2f=h2(i-2), h3f=h3(i-3).
// Iter i computes cell1->h1(i), cell2->h2(i-1), cell3->h3(i-2), and the
// head reads pre-update h3f -> out(i-3). All four streams independent ->
// 3-4x ILP inside one wave (we are latency-bound at 1 wave/SIMD).
// Warmup: bias element gated to 0 for cell2 (i<1) / cell3 (i<2): an
// all-zero B keeps (c,h) exactly zero. Tail iters (i>=TT) compute finite
// garbage that is never stored.
__global__ __launch_bounds__(64) __attribute__((amdgpu_waves_per_eu(1, 1)))
void lstm3_mfma(const float* __restrict__ input,
                const float* __restrict__ w_ih1, const float* __restrict__ w_hh1,
                const float* __restrict__ b_ih1, const float* __restrict__ b_hh1,
                const float* __restrict__ w_ih2, const float* __restrict__ w_hh2,
                const float* __restrict__ b_ih2, const float* __restrict__ b_hh2,
                const float* __restrict__ w_ih3, const float* __restrict__ w_hh3,
                const float* __restrict__ b_ih3, const float* __restrict__ b_hh3,
                const float* __restrict__ w_lin, const float* __restrict__ b_lin,
                float* __restrict__ out)
{
    const int lane = threadIdx.x & 63;
    const int n = lane & 15;          // element (B-col) AND unit-row (A-m) index
    const int q = lane >> 4;          // quad
    const bool q3 = (q == 3);

    // ---- A fragments (static, f16, interleaved-K layout) ----
    half8 a1[4], a2[4], a3[4];
#pragma unroll
    for (int g = 0; g < 4; ++g) {
        half8 t1 = {}, t2 = {}, t3 = {};
#pragma unroll
        for (int j = 0; j < 8; ++j) {
            const int u = 4 * q + (j & 3);
            const bool isin = (j < 4);
            float v1 = 0.f, v2 = 0.f, v3 = 0.f;
            if (n < NH) {   // m = n; pad row m=15 stays zero
                const int r = g * NH + n;
                if (isin) {
                    v1 = (u < NH) ? w_hh1[r * NH + u] : w_ih1[r];   // u15 = x col
                    v2 = (u < NH) ? w_ih2[r * NH + u] : 0.f;
                    v3 = (u < NH) ? w_ih3[r * NH + u] : 0.f;
                } else {
                    v1 = (u < NH) ? 0.f               : (b_ih1[r] + b_hh1[r]);
                    v2 = (u < NH) ? w_hh2[r * NH + u] : (b_ih2[r] + b_hh2[r]);
                    v3 = (u < NH) ? w_hh3[r * NH + u] : (b_ih3[r] + b_hh3[r]);
                }
            }
            t1[j] = (_Float16)v1; t2[j] = (_Float16)v2; t3[j] = (_Float16)v3;
        }
        a1[g] = t1; a2[g] = t2; a3[g] = t3;
    }

    // head weights: partial dot over this lane's 4 units
    float wl[4];
#pragma unroll
    for (int r = 0; r < 4; ++r) {
        const int u = 4 * q + r;
        wl[r] = (u < NH) ? w_lin[u] : 0.f;
    }
    const float blv = b_lin[0];

    const f32x4 z4 = {0.f, 0.f, 0.f, 0.f};

    // ---- state: lane (q,n) holds units 4q+r of element n ----
    float h1f[4] = {0.f, 0.f, 0.f, 0.f}, c1f[4] = {0.f, 0.f, 0.f, 0.f};
    float h2f[4] = {0.f, 0.f, 0.f, 0.f}, c2f[4] = {0.f, 0.f, 0.f, 0.f};
    float h3f[4] = {0.f, 0.f, 0.f, 0.f}, c3f[4] = {0.f, 0.f, 0.f, 0.f};

    const float* xrow = input + (size_t)(blockIdx.x * 16 + n) * TT;
    float* orow = out + (size_t)(blockIdx.x * 16 + n) * TT;

#define CELL_UPDATE(A, Bf, HF, CF) { \
    f32x4 d0 = __builtin_amdgcn_mfma_f32_16x16x32_f16(A[0], (Bf), z4, 0, 0, 0); \
    f32x4 d1 = __builtin_amdgcn_mfma_f32_16x16x32_f16(A[1], (Bf), z4, 0, 0, 0); \
    f32x4 d2 = __builtin_amdgcn_mfma_f32_16x16x32_f16(A[2], (Bf), z4, 0, 0, 0); \
    f32x4 d3 = __builtin_amdgcn_mfma_f32_16x16x32_f16(A[3], (Bf), z4, 0, 0, 0); \
    _Pragma("unroll") \
    for (int r = 0; r < 4; ++r) { \
        const float iv = SIGM(d0[r]); \
        const float fv = SIGM(d1[r]); \
        const float gv = TANHF(d2[r]); \
        const float ov = SIGM(d3[r]); \
        CF[r] = fmaf(fv, CF[r], iv * gv); \
        HF[r] = ov * TANHF(CF[r]); \
    } }

    float xtile = xrow[q];            // x for t = t0..t0+3 lives in quads 0..3
    float xtile_n = xrow[4 + q];      // next tile prefetch
    // x(0) broadcast (phase 0): src lane = 0*16 + n
    float xv = __int_as_float(BPERM(n * 4, __float_as_int(xtile)));
    float ysel = 0.f;
    const int bcast_base = n * 4;

#pragma unroll 1
    for (int t0 = 0; t0 < TT + 4; t0 += 4) {     // i = t0+ph, runs to TT+3
#pragma unroll
        for (int ph = 0; ph < 4; ++ph) {
            // ---- head (independent): out(i-3) from pre-update h3f ----
            float p = fmaf(wl[0], h3f[0],
                      fmaf(wl[1], h3f[1],
                      fmaf(wl[2], h3f[2], wl[3] * h3f[3])));
            p += __shfl_xor(p, 16, 64);   // sum across quads (same column n)
            p += __shfl_xor(p, 32, 64);
            const int pho = (ph + 1) & 3; // = (i-3)&3
            ysel = (q == pho) ? (p + blv) : ysel;

            // ---- pipelined broadcast of x(i+1) (used next iteration) ----
            const float xsrc = (ph == 3) ? xtile_n : xtile;
            const float xv_n = __int_as_float(
                BPERM(((ph + 1) & 3) * 64 + bcast_base, __float_as_int(xsrc)));

            // ---- lane-local B fragments from pre-update state ----
            const int pA1 = PKRTZ_I(h1f[0], h1f[1]);
            const int pB1 = PKRTZ_I(h1f[2], h1f[3]);   // q3 high = pad = 0
            const int pA2 = PKRTZ_I(h2f[0], h2f[1]);
            const int pB2 = PKRTZ_I(h2f[2], h2f[3]);
            const int pA3 = PKRTZ_I(h3f[0], h3f[1]);
            const int pB3 = PKRTZ_I(h3f[2], h3f[3]);

            const float bias2v = (ph >= 1 || t0 > 0) ? 1.0f : 0.0f;
            const float bias3v = (ph >= 2 || t0 > 0) ? 1.0f : 0.0f;

            // cell1: in = h1_prev (+x at k=27), own = {bias at k=31}
            const int4v b1 = { pA1,
                               q3 ? PKRTZ_I(h1f[2], xv) : pB1,
                               0,
                               q3 ? 0x3C000000 : 0 };
            // cell2: in = h1(i-1), own = h2(i-2) (+bias at k=31)
            const int4v b2 = { pA1, pB1, pA2,
                               q3 ? PKRTZ_I(h2f[2], bias2v) : pB2 };
            // cell3: in = h2(i-2), own = h3(i-3) (+bias at k=31)
            const int4v b3 = { pA2, pB2, pA3,
                               q3 ? PKRTZ_I(h3f[2], bias3v) : pB3 };

            const half8 B1 = __builtin_bit_cast(half8, b1);
            const half8 B2 = __builtin_bit_cast(half8, b2);
            const half8 B3 = __builtin_bit_cast(half8, b3);

            // ---- three independent cell updates (interleave freely) ----
            CELL_UPDATE(a1, B1, h1f, c1f)
            CELL_UPDATE(a2, B2, h2f, c2f)
            CELL_UPDATE(a3, B3, h3f, c3f)

            xv = xv_n;

            if (ph == 2) {                 // all 4 ysel phases complete here
                if (t0 >= 4) orow[t0 - 4 + q] = ysel;
            }
        }
        // tile advance + prefetch (clamped reads are discarded garbage)
        xtile = xtile_n;
        const int tn = t0 + 8 + q;
        xtile_n = xrow[(tn < TT) ? tn : q];
    }
#undef CELL_UPDATE
}

extern "C" void kernel_launch(void* const* d_in, const int* in_sizes, int n_in,
                              void* d_out, int out_size, void* d_ws, size_t ws_size,
                              hipStream_t stream) {
    const float* input = (const float*)d_in[0];
    const float* w_ih1 = (const float*)d_in[1];
    const float* w_hh1 = (const float*)d_in[2];
    const float* b_ih1 = (const float*)d_in[3];
    const float* b_hh1 = (const float*)d_in[4];
    const float* w_ih2 = (const float*)d_in[5];
    const float* w_hh2 = (const float*)d_in[6];
    const float* b_ih2 = (const float*)d_in[7];
    const float* b_hh2 = (const float*)d_in[8];
    const float* w_ih3 = (const float*)d_in[9];
    const float* w_hh3 = (const float*)d_in[10];
    const float* b_ih3 = (const float*)d_in[11];
    const float* b_hh3 = (const float*)d_in[12];
    const float* w_lin = (const float*)d_in[13];
    const float* b_lin = (const float*)d_in[14];
    float* out = (float*)d_out;

    const int B = in_sizes[0] / TT;      // 8192
    const int blocks = B / 16;           // 512 waves, 16 elems each

    lstm3_mfma<<<blocks, 64, 0, stream>>>(
        input, w_ih1, w_hh1, b_ih1, b_hh1,
        w_ih2, w_hh2, b_ih2, b_hh2,
        w_ih3, w_hh3, b_ih3, b_hh3,
        w_lin, b_lin, out);
}